// Round 7
// baseline (158.292 us; speedup 1.0000x reference)
//
#include <hip/hip_runtime.h>
#include <math.h>

#define D 128

typedef float f32x2 __attribute__((ext_vector_type(2)));
typedef float f32x4 __attribute__((ext_vector_type(4)));
typedef short short8 __attribute__((ext_vector_type(8)));

__device__ __forceinline__ float softplusf(float z){
    return log1pf(expf(-fabsf(z))) + fmaxf(z, 0.f);
}
__device__ __forceinline__ unsigned short f2bf(float f){
    unsigned u = __float_as_uint(f);
    u += 0x7fffu + ((u >> 16) & 1u);          // round-to-nearest-even
    return (unsigned short)(u >> 16);
}

// ---- prep: W1 -> MFMA-fragment-ordered bf16 (blocks 0..7) | pre (block 8) ----
// fragment: wf[((nt*4+kc)*64 + l)*8 + j] = bf16(W1[k][c]),
//   c = nt*16 + (l&15), k = kc*32 + (l>>4)*8 + j
__global__ void __launch_bounds__(256) k_prep(
    const float* __restrict__ W1, unsigned short* __restrict__ wf,
    const float* __restrict__ W2, const float* __restrict__ b2,
    const float* __restrict__ Wp, const float* __restrict__ bp,
    float* __restrict__ v, float* __restrict__ cconst)
{
    __shared__ float wps[D];
    const int b = blockIdx.x;
    const int tid = threadIdx.x;
    if (b < 8){
        int kc = tid >> 6, l = tid & 63;
        int c  = b*16 + (l & 15);
        int kb = kc*32 + (l >> 4)*8;
        union { unsigned short us[8]; short8 s; } uu;
        #pragma unroll
        for (int j = 0; j < 8; ++j) uu.us[j] = f2bf(W1[(size_t)(kb+j)*D + c]);
        *(short8*)&wf[((size_t)(b*4 + kc)*64 + l)*8] = uu.s;
    } else {
        // ---- pre: wps = rowsum(Wp); v = W2 @ wps; cconst = b2.wps + sum(bp) ----
        int lane = tid & 63, wid = tid >> 6;
        for (int r = wid; r < D; r += 4){
            float a = Wp[(size_t)r*D + lane] + Wp[(size_t)r*D + 64 + lane];
            for (int off=32; off>0; off>>=1) a += __shfl_down(a, off);
            if (lane == 0) wps[r] = a;
        }
        __syncthreads();
        float wl0 = wps[lane], wl1 = wps[64 + lane];
        for (int r = wid; r < D; r += 4){
            float a = W2[(size_t)r*D + lane]*wl0 + W2[(size_t)r*D + 64 + lane]*wl1;
            for (int off=32; off>0; off>>=1) a += __shfl_down(a, off);
            if (lane == 0) v[r] = a;
        }
        if (wid == 0){
            float a = b2[lane]*wl0 + b2[64+lane]*wl1 + bp[lane] + bp[64+lane];
            for (int off=32; off>0; off>>=1) a += __shfl_down(a, off);
            if (lane == 0) cconst[0] = a;
        }
    }
}

// ---- fused: xw8 = fp8(x @ W1) via MFMA (no LDS, no barrier) | deg count ----
__global__ void __launch_bounds__(256) k_fused1(
    const float* __restrict__ x, const unsigned short* __restrict__ wf,
    unsigned* __restrict__ xw8, int N,
    const int* __restrict__ edst, int* __restrict__ deg, int E, int nGemm)
{
    const int b = blockIdx.x;
    const int tid = threadIdx.x;
    if (b < nGemm){
        const int l = tid & 63, w = tid >> 6;
        const int r  = b*64 + w*16 + (l & 15);      // this lane's output row
        const int kb = (l >> 4) * 8;
        // x row -> bf16 A-fragments (packed converts)
        short8 a[4];
        #pragma unroll
        for (int kc = 0; kc < 4; ++kc){
            float4 f0 = make_float4(0.f,0.f,0.f,0.f), f1 = f0;
            if (r < N){
                const float* px = &x[(size_t)r*D + kc*32 + kb];
                f0 = *(const float4*)px;
                f1 = *(const float4*)(px + 4);
            }
            unsigned u0,u1,u2,u3;
            asm("v_cvt_pk_bf16_f32 %0, %1, %2" : "=v"(u0) : "v"(f0.x), "v"(f0.y));
            asm("v_cvt_pk_bf16_f32 %0, %1, %2" : "=v"(u1) : "v"(f0.z), "v"(f0.w));
            asm("v_cvt_pk_bf16_f32 %0, %1, %2" : "=v"(u2) : "v"(f1.x), "v"(f1.y));
            asm("v_cvt_pk_bf16_f32 %0, %1, %2" : "=v"(u3) : "v"(f1.z), "v"(f1.w));
            union { unsigned u[4]; short8 s; } uu = {{u0, u1, u2, u3}};
            a[kc] = uu.s;
        }
        const short8* __restrict__ wfr = (const short8*)wf;
        #pragma unroll
        for (int nt = 0; nt < 8; ++nt){
            f32x4 acc = {0.f, 0.f, 0.f, 0.f};
            #pragma unroll
            for (int kc = 0; kc < 4; ++kc)
                acc = __builtin_amdgcn_mfma_f32_16x16x32_bf16(
                          wfr[(nt*4 + kc)*64 + l], a[kc], acc, 0, 0, 0);
            // D = C^T: lane holds cols nt*16+(l>>4)*4+{0..3} of row r -> 1 dword
            int pk = __builtin_amdgcn_cvt_pk_fp8_f32(acc[0], acc[1], 0, false);
            pk     = __builtin_amdgcn_cvt_pk_fp8_f32(acc[2], acc[3], pk, true);
            if (r < N) xw8[(size_t)r*32 + nt*4 + (l >> 4)] = (unsigned)pk;
        }
    } else {
        int e = (b - nGemm)*256 + tid;
        if (e < E) atomicAdd(&deg[edst[e]], 1);
    }
}

// ---- exclusive scan of deg (1024/block) via wave shfl-scan ----
__global__ void k_scanA(const int* __restrict__ deg, int* __restrict__ offs,
                        int* __restrict__ bsum, int N){
    __shared__ int wsums[16];
    __shared__ int gtot;
    int tid = threadIdx.x, lane = tid & 63, wid = tid >> 6;
    int g = blockIdx.x*1024 + tid;
    int val = (g < N) ? deg[g] : 0;
    int inc = val;
    #pragma unroll
    for (int off=1; off<64; off<<=1){
        int t = __shfl_up(inc, off);
        if (lane >= off) inc += t;
    }
    if (lane == 63) wsums[wid] = inc;
    __syncthreads();
    if (wid == 0 && lane < 16){
        int t = wsums[lane];
        int i2 = t;
        #pragma unroll
        for (int off=1; off<16; off<<=1){
            int u = __shfl_up(i2, off);
            if (lane >= off) i2 += u;
        }
        wsums[lane] = i2 - t;           // exclusive
        if (lane == 15) gtot = i2;
    }
    __syncthreads();
    if (g < N) offs[g] = wsums[wid] + inc - val;
    if (tid == 0) bsum[blockIdx.x] = gtot;
}

// ---- finalize: cross-block prefix (nb<=64), offs, cursor, norm, ep ----
__global__ void k_scanC(int* __restrict__ offs, const int* __restrict__ bsum,
                        int* __restrict__ cursor, const int* __restrict__ deg,
                        float* __restrict__ norm, int2* __restrict__ ep,
                        const int* __restrict__ perm, int N){
    __shared__ int sbase;
    int tid = threadIdx.x;
    if (tid < 64){
        int val = (tid < (int)blockIdx.x) ? bsum[tid] : 0;
        for (int off=32; off>0; off>>=1) val += __shfl_down(val, off);
        if (tid == 0) sbase = val;
    }
    __syncthreads();
    int g = blockIdx.x*1024 + tid;
    if (g < N){
        int o = offs[g] + sbase;
        offs[g] = o;
        cursor[g] = o;
        float nm = rsqrtf(fmaxf((float)deg[g], 1.f));
        norm[g] = nm;
        ep[g] = make_int2(perm[g], __float_as_int(nm));
    }
}

// ---- fill CSR (src ids grouped by dst, uint16) ----
__global__ void k_fill(const int* __restrict__ src, const int* __restrict__ dst,
                       int* __restrict__ cursor, unsigned short* __restrict__ csr, int E){
    int e = blockIdx.x*blockDim.x + threadIdx.x;
    if (e < E){
        int dd = dst[e];
        int p = atomicAdd(&cursor[dd], 1);
        csr[p] = (unsigned short)src[e];
    }
}

#define FMA8(u, nk) { \
    f32x2 f01 = __builtin_amdgcn_cvt_pk_f32_fp8((int)(u), false); \
    f32x2 f23 = __builtin_amdgcn_cvt_pk_f32_fp8((int)(u), true);  \
    ac.x = fmaf(f01.x, (nk), ac.x); ac.y = fmaf(f01.y, (nk), ac.y); \
    ac.z = fmaf(f23.x, (nk), ac.z); ac.w = fmaf(f23.y, (nk), ac.w); }

// ---- fused layer-1 agg (clean lanes 0-31, corrupt lanes 32-63) + relu + dot(v) ----
__global__ void __launch_bounds__(256) k_agg(const unsigned* __restrict__ xw8,
                     const unsigned short* __restrict__ csr, const int* __restrict__ offs,
                     const int* __restrict__ deg, const float* __restrict__ norm,
                     const int2* __restrict__ ep, const float* __restrict__ b1,
                     const float* __restrict__ v, float2* __restrict__ t2, int N){
    int w = threadIdx.x >> 6;
    int lane = threadIdx.x & 63;
    int i = blockIdx.x*4 + w;
    if (i >= N) return;
    int half = lane >> 5;
    int c = lane & 31;                                // uint column (4 dims)
    const unsigned* __restrict__ xr = xw8;            // row stride 32 uints (128B)
    float4 ac = make_float4(0.f,0.f,0.f,0.f);
    int start = offs[i], cnt = deg[i];

    for (int base = 0; base < cnt; base += 64){
        int m = min(cnt - base, 64);
        int s = 0, sp = 0; float ns = 0.f;
        if (lane < m){
            s = csr[start + base + lane];
            int2 e = ep[s];
            sp = e.x; ns = __int_as_float(e.y);
        }
        int k = 0;
        for (; k + 4 <= m; k += 4){
            int ra0=__shfl(s,k  ), rb0=__shfl(sp,k  ); float n0=__shfl(ns,k  );
            int ra1=__shfl(s,k+1), rb1=__shfl(sp,k+1); float n1=__shfl(ns,k+1);
            int ra2=__shfl(s,k+2), rb2=__shfl(sp,k+2); float n2=__shfl(ns,k+2);
            int ra3=__shfl(s,k+3), rb3=__shfl(sp,k+3); float n3=__shfl(ns,k+3);
            int r0 = half ? rb0 : ra0;
            int r1 = half ? rb1 : ra1;
            int r2 = half ? rb2 : ra2;
            int r3 = half ? rb3 : ra3;
            unsigned d0 = xr[(size_t)r0*32 + c];
            unsigned d1 = xr[(size_t)r1*32 + c];
            unsigned d2 = xr[(size_t)r2*32 + c];
            unsigned d3 = xr[(size_t)r3*32 + c];
            FMA8(d0, n0); FMA8(d1, n1); FMA8(d2, n2); FMA8(d3, n3);
        }
        for (; k < m; ++k){
            int ra=__shfl(s,k), rb=__shfl(sp,k); float nk=__shfl(ns,k);
            int r = half ? rb : ra;
            unsigned dv = xr[(size_t)r*32 + c];
            FMA8(dv, nk);
        }
    }
    float ni = norm[i];
    float4 bb = ((const float4*)b1)[c];
    float4 vv = ((const float4*)v)[c];
    float p = fmaxf(fmaf(ac.x, ni, bb.x), 0.f)*vv.x
            + fmaxf(fmaf(ac.y, ni, bb.y), 0.f)*vv.y
            + fmaxf(fmaf(ac.z, ni, bb.z), 0.f)*vv.z
            + fmaxf(fmaf(ac.w, ni, bb.w), 0.f)*vv.w;
    for (int off=16; off>0; off>>=1) p += __shfl_xor(p, off);
    float pd = __shfl(p, 32);
    if (lane == 0) t2[i] = make_float2(ni*p, ni*pd);
}

// ---- layer-2 scalar gather + loss + final (last-block) ----
__global__ void k_loss(const float2* __restrict__ t2, const unsigned short* __restrict__ csr,
                       const int* __restrict__ offs, const int* __restrict__ deg,
                       const float* __restrict__ norm, const float* __restrict__ cconst,
                       float* __restrict__ acc, unsigned* __restrict__ done,
                       float* __restrict__ out, int N, int nblocks){
    int i = blockIdx.x*blockDim.x + threadIdx.x;
    float li = 0.f;
    if (i < N){
        int start = offs[i], cnt = deg[i];
        float sc = 0.f, sd = 0.f;
        for (int k=0;k<cnt;k++){
            int s = csr[start+k];
            float2 t = t2[s];
            sc += t.x; sd += t.y;
        }
        float ni = norm[i], C = cconst[0];
        li = softplusf(-fmaf(ni, sc, C)) + softplusf(fmaf(ni, sd, C));
    }
    for (int off=32; off>0; off>>=1) li += __shfl_down(li, off);
    __shared__ float wsum[4];
    int lane = threadIdx.x & 63, wid = threadIdx.x >> 6;
    if (lane == 0) wsum[wid] = li;
    __syncthreads();
    if (threadIdx.x == 0){
        float s = wsum[0] + wsum[1] + wsum[2] + wsum[3];
        atomicAdd(acc, s);
        __threadfence();
        unsigned t = atomicAdd(done, 1u);
        if (t == (unsigned)(nblocks - 1)){
            float tot = atomicAdd(acc, 0.0f);
            out[0] = tot / (float)(2*N);
        }
    }
}

extern "C" void kernel_launch(void* const* d_in, const int* in_sizes, int n_in,
                              void* d_out, int out_size, void* d_ws, size_t ws_size,
                              hipStream_t stream){
    const float* x    = (const float*)d_in[0];
    const float* W1   = (const float*)d_in[1];
    const float* b1   = (const float*)d_in[2];
    const float* W2   = (const float*)d_in[3];
    const float* b2   = (const float*)d_in[4];
    const float* Wp   = (const float*)d_in[5];
    const float* bp   = (const float*)d_in[6];
    const int*   esrc = (const int*)d_in[7];
    const int*   edst = (const int*)d_in[8];
    const int*   perm = (const int*)d_in[9];
    const int N = in_sizes[0] / D;
    const int E = in_sizes[7];

    char* ws = (char*)d_ws;
    size_t off = 0;
    auto alloc = [&](size_t bytes)->void*{
        void* p = ws + off;
        off += (bytes + 255) & ~(size_t)255;
        return p;
    };
    unsigned* xw8 = (unsigned*)alloc((size_t)N*32*sizeof(unsigned));   // fp8 rows, 128B
    unsigned short* wf = (unsigned short*)alloc((size_t)D*D*sizeof(unsigned short)); // W1 frags
    int*   deg    = (int*)  alloc((size_t)N*sizeof(int));
    float* norm   = (float*)alloc((size_t)N*sizeof(float));
    int*   offs   = (int*)  alloc((size_t)N*sizeof(int));
    int*   cursor = (int*)  alloc((size_t)N*sizeof(int));
    int2*  ep     = (int2*) alloc((size_t)N*sizeof(int2));
    unsigned short* csr = (unsigned short*)alloc((size_t)E*sizeof(unsigned short));
    float2* t2    = (float2*)alloc((size_t)N*sizeof(float2));
    int*   bsum   = (int*)  alloc(4096);
    float* v      = (float*)alloc(D*sizeof(float));
    float* cconst = (float*)alloc(256);
    float* acc    = (float*)alloc(256);
    unsigned* done = (unsigned*)(acc + 1);

    hipMemsetAsync(deg, 0, (size_t)N*sizeof(int), stream);
    hipMemsetAsync(acc, 0, 256, stream);

    int nGemm = (N + 63) / 64;
    int nDeg  = (E + 255) / 256;
    int nb    = (N + 1023) / 1024;
    int nLoss = (N + 255) / 256;

    k_prep  <<<9, 256, 0, stream>>>(W1, wf, W2, b2, Wp, bp, v, cconst);
    k_fused1<<<nGemm + nDeg, 256, 0, stream>>>(x, wf, xw8, N, edst, deg, E, nGemm);
    k_scanA <<<nb, 1024, 0, stream>>>(deg, offs, bsum, N);
    k_scanC <<<nb, 1024, 0, stream>>>(offs, bsum, cursor, deg, norm, ep, perm, N);
    k_fill  <<<(E+255)/256, 256, 0, stream>>>(esrc, edst, cursor, csr, E);
    k_agg   <<<(N+3)/4, 256, 0, stream>>>(xw8, csr, offs, deg, norm, ep, b1, v, t2, N);
    k_loss  <<<nLoss, 256, 0, stream>>>(t2, csr, offs, deg, norm, cconst, acc, done,
                                        (float*)d_out, N, nLoss);
}

// Round 10
// 157.002 us; speedup vs baseline: 1.0082x; 1.0082x over previous
//
#include <hip/hip_runtime.h>
#include <math.h>

#define D 128

typedef float f32x2 __attribute__((ext_vector_type(2)));
typedef float f32x4 __attribute__((ext_vector_type(4)));
typedef short short8 __attribute__((ext_vector_type(8)));

__device__ __forceinline__ float softplusf(float z){
    return log1pf(expf(-fabsf(z))) + fmaxf(z, 0.f);
}
__device__ __forceinline__ unsigned short f2bf(float f){
    unsigned u = __float_as_uint(f);
    u += 0x7fffu + ((u >> 16) & 1u);          // round-to-nearest-even
    return (unsigned short)(u >> 16);
}

// ---- prep: W1 -> MFMA-fragment-ordered bf16 (blocks 0..7) | pre (block 8) ----
__global__ void __launch_bounds__(256) k_prep(
    const float* __restrict__ W1, unsigned short* __restrict__ wf,
    const float* __restrict__ W2, const float* __restrict__ b2,
    const float* __restrict__ Wp, const float* __restrict__ bp,
    float* __restrict__ v, float* __restrict__ cconst)
{
    __shared__ float wps[D];
    const int b = blockIdx.x;
    const int tid = threadIdx.x;
    if (b < 8){
        int kc = tid >> 6, l = tid & 63;
        int c  = b*16 + (l & 15);
        int kb = kc*32 + (l >> 4)*8;
        union { unsigned short us[8]; short8 s; } uu;
        #pragma unroll
        for (int j = 0; j < 8; ++j) uu.us[j] = f2bf(W1[(size_t)(kb+j)*D + c]);
        *(short8*)&wf[((size_t)(b*4 + kc)*64 + l)*8] = uu.s;
    } else {
        int lane = tid & 63, wid = tid >> 6;
        for (int r = wid; r < D; r += 4){
            float a = Wp[(size_t)r*D + lane] + Wp[(size_t)r*D + 64 + lane];
            for (int off=32; off>0; off>>=1) a += __shfl_down(a, off);
            if (lane == 0) wps[r] = a;
        }
        __syncthreads();
        float wl0 = wps[lane], wl1 = wps[64 + lane];
        for (int r = wid; r < D; r += 4){
            float a = W2[(size_t)r*D + lane]*wl0 + W2[(size_t)r*D + 64 + lane]*wl1;
            for (int off=32; off>0; off>>=1) a += __shfl_down(a, off);
            if (lane == 0) v[r] = a;
        }
        if (wid == 0){
            float a = b2[lane]*wl0 + b2[64+lane]*wl1 + bp[lane] + bp[64+lane];
            for (int off=32; off>0; off>>=1) a += __shfl_down(a, off);
            if (lane == 0) cconst[0] = a;
        }
    }
}

// ---- fused: xw8 = fp8(x @ W1) via MFMA (no LDS, no barrier) | deg count ----
__global__ void __launch_bounds__(256) k_fused1(
    const float* __restrict__ x, const unsigned short* __restrict__ wf,
    unsigned* __restrict__ xw8, int N,
    const int* __restrict__ edst, int* __restrict__ deg, int E, int nGemm)
{
    const int b = blockIdx.x;
    const int tid = threadIdx.x;
    if (b < nGemm){
        const int l = tid & 63, w = tid >> 6;
        const int r  = b*64 + w*16 + (l & 15);      // this lane's output row
        const int kb = (l >> 4) * 8;
        short8 a[4];
        #pragma unroll
        for (int kc = 0; kc < 4; ++kc){
            float4 f0 = make_float4(0.f,0.f,0.f,0.f), f1 = f0;
            if (r < N){
                const float* px = &x[(size_t)r*D + kc*32 + kb];
                f0 = *(const float4*)px;
                f1 = *(const float4*)(px + 4);
            }
            unsigned u0,u1,u2,u3;
            asm("v_cvt_pk_bf16_f32 %0, %1, %2" : "=v"(u0) : "v"(f0.x), "v"(f0.y));
            asm("v_cvt_pk_bf16_f32 %0, %1, %2" : "=v"(u1) : "v"(f0.z), "v"(f0.w));
            asm("v_cvt_pk_bf16_f32 %0, %1, %2" : "=v"(u2) : "v"(f1.x), "v"(f1.y));
            asm("v_cvt_pk_bf16_f32 %0, %1, %2" : "=v"(u3) : "v"(f1.z), "v"(f1.w));
            union { unsigned u[4]; short8 s; } uu = {{u0, u1, u2, u3}};
            a[kc] = uu.s;
        }
        const short8* __restrict__ wfr = (const short8*)wf;
        #pragma unroll
        for (int nt = 0; nt < 8; ++nt){
            f32x4 acc = {0.f, 0.f, 0.f, 0.f};
            #pragma unroll
            for (int kc = 0; kc < 4; ++kc)
                acc = __builtin_amdgcn_mfma_f32_16x16x32_bf16(
                          wfr[(nt*4 + kc)*64 + l], a[kc], acc, 0, 0, 0);
            int pk = __builtin_amdgcn_cvt_pk_fp8_f32(acc[0], acc[1], 0, false);
            pk     = __builtin_amdgcn_cvt_pk_fp8_f32(acc[2], acc[3], pk, true);
            if (r < N) xw8[(size_t)r*32 + nt*4 + (l >> 4)] = (unsigned)pk;
        }
    } else {
        int e = (b - nGemm)*256 + tid;
        if (e < E) atomicAdd(&deg[edst[e]], 1);
    }
}

// ---- exclusive scan of deg (1024/block) via wave shfl-scan ----
__global__ void k_scanA(const int* __restrict__ deg, int* __restrict__ offs,
                        int* __restrict__ bsum, int N){
    __shared__ int wsums[16];
    __shared__ int gtot;
    int tid = threadIdx.x, lane = tid & 63, wid = tid >> 6;
    int g = blockIdx.x*1024 + tid;
    int val = (g < N) ? deg[g] : 0;
    int inc = val;
    #pragma unroll
    for (int off=1; off<64; off<<=1){
        int t = __shfl_up(inc, off);
        if (lane >= off) inc += t;
    }
    if (lane == 63) wsums[wid] = inc;
    __syncthreads();
    if (wid == 0 && lane < 16){
        int t = wsums[lane];
        int i2 = t;
        #pragma unroll
        for (int off=1; off<16; off<<=1){
            int u = __shfl_up(i2, off);
            if (lane >= off) i2 += u;
        }
        wsums[lane] = i2 - t;           // exclusive
        if (lane == 15) gtot = i2;
    }
    __syncthreads();
    if (g < N) offs[g] = wsums[wid] + inc - val;
    if (tid == 0) bsum[blockIdx.x] = gtot;
}

// ---- finalize: cross-block prefix (nb<=64), offs, cursor, norm, ep ----
__global__ void k_scanC(int* __restrict__ offs, const int* __restrict__ bsum,
                        int* __restrict__ cursor, const int* __restrict__ deg,
                        float* __restrict__ norm, int2* __restrict__ ep,
                        const int* __restrict__ perm, int N){
    __shared__ int sbase;
    int tid = threadIdx.x;
    if (tid < 64){
        int val = (tid < (int)blockIdx.x) ? bsum[tid] : 0;
        for (int off=32; off>0; off>>=1) val += __shfl_down(val, off);
        if (tid == 0) sbase = val;
    }
    __syncthreads();
    int g = blockIdx.x*1024 + tid;
    if (g < N){
        int o = offs[g] + sbase;
        offs[g] = o;
        cursor[g] = o;
        float nm = rsqrtf(fmaxf((float)deg[g], 1.f));
        norm[g] = nm;
        ep[g] = make_int2(perm[g], __float_as_int(nm));
    }
}

// ---- fill CSR (src ids grouped by dst, uint16) ----
__global__ void k_fill(const int* __restrict__ src, const int* __restrict__ dst,
                       int* __restrict__ cursor, unsigned short* __restrict__ csr, int E){
    int e = blockIdx.x*blockDim.x + threadIdx.x;
    if (e < E){
        int dd = dst[e];
        int p = atomicAdd(&cursor[dd], 1);
        csr[p] = (unsigned short)src[e];
    }
}

#define FMA8(u, nk) { \
    f32x2 f01 = __builtin_amdgcn_cvt_pk_f32_fp8((int)(u), false); \
    f32x2 f23 = __builtin_amdgcn_cvt_pk_f32_fp8((int)(u), true);  \
    ac.x = fmaf(f01.x, (nk), ac.x); ac.y = fmaf(f01.y, (nk), ac.y); \
    ac.z = fmaf(f23.x, (nk), ac.z); ac.w = fmaf(f23.y, (nk), ac.w); }

// ---- fused layer-1 agg (clean lanes 0-31, corrupt lanes 32-63) + relu + dot(v) ----
// round-6 proven shuffle structure; {s,sp} packed -> 2 shuffles/edge instead of 3
__global__ void __launch_bounds__(256) k_agg(const unsigned* __restrict__ xw8,
                     const unsigned short* __restrict__ csr, const int* __restrict__ offs,
                     const int* __restrict__ deg, const float* __restrict__ norm,
                     const int2* __restrict__ ep, const float* __restrict__ b1,
                     const float* __restrict__ v, float2* __restrict__ t2, int N){
    int w = threadIdx.x >> 6;
    int lane = threadIdx.x & 63;
    int i = blockIdx.x*4 + w;
    if (i >= N) return;
    int half = lane >> 5;
    int sh = half << 4;                               // 0 or 16
    int c = lane & 31;                                // uint column (4 dims)
    const unsigned* __restrict__ xr = xw8;            // row stride 32 uints (128B)
    float4 ac = make_float4(0.f,0.f,0.f,0.f);
    int start = offs[i], cnt = deg[i];

    for (int base = 0; base < cnt; base += 64){
        int m = min(cnt - base, 64);
        int ssp = 0; float ns = 0.f;
        if (lane < m){
            int s = csr[start + base + lane];
            int2 e = ep[s];
            ssp = s | (e.x << 16);
            ns = __int_as_float(e.y);
        }
        int k = 0;
        for (; k + 4 <= m; k += 4){
            int p0=__shfl(ssp,k  ); float n0=__shfl(ns,k  );
            int p1=__shfl(ssp,k+1); float n1=__shfl(ns,k+1);
            int p2=__shfl(ssp,k+2); float n2=__shfl(ns,k+2);
            int p3=__shfl(ssp,k+3); float n3=__shfl(ns,k+3);
            unsigned r0 = ((unsigned)p0 >> sh) & 0xffffu;
            unsigned r1 = ((unsigned)p1 >> sh) & 0xffffu;
            unsigned r2 = ((unsigned)p2 >> sh) & 0xffffu;
            unsigned r3 = ((unsigned)p3 >> sh) & 0xffffu;
            unsigned d0 = xr[(size_t)r0*32 + c];
            unsigned d1 = xr[(size_t)r1*32 + c];
            unsigned d2 = xr[(size_t)r2*32 + c];
            unsigned d3 = xr[(size_t)r3*32 + c];
            FMA8(d0, n0); FMA8(d1, n1); FMA8(d2, n2); FMA8(d3, n3);
        }
        for (; k < m; ++k){
            int pk_=__shfl(ssp,k); float nk=__shfl(ns,k);
            unsigned r = ((unsigned)pk_ >> sh) & 0xffffu;
            unsigned dv = xr[(size_t)r*32 + c];
            FMA8(dv, nk);
        }
    }
    float ni = norm[i];
    float4 bb = ((const float4*)b1)[c];
    float4 vv = ((const float4*)v)[c];
    float p = fmaxf(fmaf(ac.x, ni, bb.x), 0.f)*vv.x
            + fmaxf(fmaf(ac.y, ni, bb.y), 0.f)*vv.y
            + fmaxf(fmaf(ac.z, ni, bb.z), 0.f)*vv.z
            + fmaxf(fmaf(ac.w, ni, bb.w), 0.f)*vv.w;
    for (int off=16; off>0; off>>=1) p += __shfl_xor(p, off);
    float pd = __shfl(p, 32);
    if (lane == 0) t2[i] = make_float2(ni*p, ni*pd);
}

// ---- layer-2 scalar gather + loss + final (last-block) ----
__global__ void k_loss(const float2* __restrict__ t2, const unsigned short* __restrict__ csr,
                       const int* __restrict__ offs, const int* __restrict__ deg,
                       const float* __restrict__ norm, const float* __restrict__ cconst,
                       float* __restrict__ acc, unsigned* __restrict__ done,
                       float* __restrict__ out, int N, int nblocks){
    int i = blockIdx.x*blockDim.x + threadIdx.x;
    float li = 0.f;
    if (i < N){
        int start = offs[i], cnt = deg[i];
        float sc = 0.f, sd = 0.f;
        for (int k=0;k<cnt;k++){
            int s = csr[start+k];
            float2 t = t2[s];
            sc += t.x; sd += t.y;
        }
        float ni = norm[i], C = cconst[0];
        li = softplusf(-fmaf(ni, sc, C)) + softplusf(fmaf(ni, sd, C));
    }
    for (int off=32; off>0; off>>=1) li += __shfl_down(li, off);
    __shared__ float wsum[4];
    int lane = threadIdx.x & 63, wid = threadIdx.x >> 6;
    if (lane == 0) wsum[wid] = li;
    __syncthreads();
    if (threadIdx.x == 0){
        float s = wsum[0] + wsum[1] + wsum[2] + wsum[3];
        atomicAdd(acc, s);
        __threadfence();
        unsigned t = atomicAdd(done, 1u);
        if (t == (unsigned)(nblocks - 1)){
            float tot = atomicAdd(acc, 0.0f);
            out[0] = tot / (float)(2*N);
        }
    }
}

extern "C" void kernel_launch(void* const* d_in, const int* in_sizes, int n_in,
                              void* d_out, int out_size, void* d_ws, size_t ws_size,
                              hipStream_t stream){
    const float* x    = (const float*)d_in[0];
    const float* W1   = (const float*)d_in[1];
    const float* b1   = (const float*)d_in[2];
    const float* W2   = (const float*)d_in[3];
    const float* b2   = (const float*)d_in[4];
    const float* Wp   = (const float*)d_in[5];
    const float* bp   = (const float*)d_in[6];
    const int*   esrc = (const int*)d_in[7];
    const int*   edst = (const int*)d_in[8];
    const int*   perm = (const int*)d_in[9];
    const int N = in_sizes[0] / D;
    const int E = in_sizes[7];

    char* ws = (char*)d_ws;
    size_t off = 0;
    auto alloc = [&](size_t bytes)->void*{
        void* p = ws + off;
        off += (bytes + 255) & ~(size_t)255;
        return p;
    };
    unsigned* xw8 = (unsigned*)alloc((size_t)N*32*sizeof(unsigned));   // fp8 rows, 128B
    unsigned short* wf = (unsigned short*)alloc((size_t)D*D*sizeof(unsigned short)); // W1 frags
    int*   deg    = (int*)  alloc((size_t)N*sizeof(int));
    float* norm   = (float*)alloc((size_t)N*sizeof(float));
    int*   offs   = (int*)  alloc((size_t)N*sizeof(int));
    int*   cursor = (int*)  alloc((size_t)N*sizeof(int));
    int2*  ep     = (int2*) alloc((size_t)N*sizeof(int2));
    unsigned short* csr = (unsigned short*)alloc((size_t)E*sizeof(unsigned short));
    float2* t2    = (float2*)alloc((size_t)N*sizeof(float2));
    int*   bsum   = (int*)  alloc(4096);
    float* v      = (float*)alloc(D*sizeof(float));
    float* cconst = (float*)alloc(256);
    float* acc    = (float*)alloc(256);
    unsigned* done = (unsigned*)(acc + 1);

    hipMemsetAsync(deg, 0, (size_t)N*sizeof(int), stream);
    hipMemsetAsync(acc, 0, 256, stream);

    int nGemm = (N + 63) / 64;
    int nDeg  = (E + 255) / 256;
    int nb    = (N + 1023) / 1024;
    int nLoss = (N + 255) / 256;

    k_prep  <<<9, 256, 0, stream>>>(W1, wf, W2, b2, Wp, bp, v, cconst);
    k_fused1<<<nGemm + nDeg, 256, 0, stream>>>(x, wf, xw8, N, edst, deg, E, nGemm);
    k_scanA <<<nb, 1024, 0, stream>>>(deg, offs, bsum, N);
    k_scanC <<<nb, 1024, 0, stream>>>(offs, bsum, cursor, deg, norm, ep, perm, N);
    k_fill  <<<(E+255)/256, 256, 0, stream>>>(esrc, edst, cursor, csr, E);
    k_agg   <<<(N+3)/4, 256, 0, stream>>>(xw8, csr, offs, deg, norm, ep, b1, v, t2, N);
    k_loss  <<<nLoss, 256, 0, stream>>>(t2, csr, offs, deg, norm, cconst, acc, done,
                                        (float*)d_out, N, nLoss);
}

// Round 11
// 156.105 us; speedup vs baseline: 1.0140x; 1.0058x over previous
//
#include <hip/hip_runtime.h>
#include <math.h>

#define D 128

typedef float f32x2 __attribute__((ext_vector_type(2)));
typedef float f32x4 __attribute__((ext_vector_type(4)));
typedef short short8 __attribute__((ext_vector_type(8)));

__device__ __forceinline__ float softplusf(float z){
    return log1pf(expf(-fabsf(z))) + fmaxf(z, 0.f);
}
__device__ __forceinline__ unsigned short f2bf(float f){
    unsigned u = __float_as_uint(f);
    u += 0x7fffu + ((u >> 16) & 1u);          // round-to-nearest-even
    return (unsigned short)(u >> 16);
}

// ---- prep: W1 -> MFMA-fragment-ordered bf16 (blocks 0..7) | pre (block 8) ----
__global__ void __launch_bounds__(256) k_prep(
    const float* __restrict__ W1, unsigned short* __restrict__ wf,
    const float* __restrict__ W2, const float* __restrict__ b2,
    const float* __restrict__ Wp, const float* __restrict__ bp,
    float* __restrict__ v, float* __restrict__ cconst)
{
    __shared__ float wps[D];
    const int b = blockIdx.x;
    const int tid = threadIdx.x;
    if (b < 8){
        int kc = tid >> 6, l = tid & 63;
        int c  = b*16 + (l & 15);
        int kb = kc*32 + (l >> 4)*8;
        union { unsigned short us[8]; short8 s; } uu;
        #pragma unroll
        for (int j = 0; j < 8; ++j) uu.us[j] = f2bf(W1[(size_t)(kb+j)*D + c]);
        *(short8*)&wf[((size_t)(b*4 + kc)*64 + l)*8] = uu.s;
    } else {
        int lane = tid & 63, wid = tid >> 6;
        for (int r = wid; r < D; r += 4){
            float a = Wp[(size_t)r*D + lane] + Wp[(size_t)r*D + 64 + lane];
            for (int off=32; off>0; off>>=1) a += __shfl_down(a, off);
            if (lane == 0) wps[r] = a;
        }
        __syncthreads();
        float wl0 = wps[lane], wl1 = wps[64 + lane];
        for (int r = wid; r < D; r += 4){
            float a = W2[(size_t)r*D + lane]*wl0 + W2[(size_t)r*D + 64 + lane]*wl1;
            for (int off=32; off>0; off>>=1) a += __shfl_down(a, off);
            if (lane == 0) v[r] = a;
        }
        if (wid == 0){
            float a = b2[lane]*wl0 + b2[64+lane]*wl1 + bp[lane] + bp[64+lane];
            for (int off=32; off>0; off>>=1) a += __shfl_down(a, off);
            if (lane == 0) cconst[0] = a;
        }
    }
}

// ---- fused: xw8 = fp8(x @ W1) via MFMA (no LDS, no barrier) | deg count ----
__global__ void __launch_bounds__(256) k_fused1(
    const float* __restrict__ x, const unsigned short* __restrict__ wf,
    unsigned* __restrict__ xw8, int N,
    const int* __restrict__ edst, int* __restrict__ deg, int E, int nGemm)
{
    const int b = blockIdx.x;
    const int tid = threadIdx.x;
    if (b < nGemm){
        const int l = tid & 63, w = tid >> 6;
        const int r  = b*64 + w*16 + (l & 15);      // this lane's output row
        const int kb = (l >> 4) * 8;
        short8 a[4];
        #pragma unroll
        for (int kc = 0; kc < 4; ++kc){
            float4 f0 = make_float4(0.f,0.f,0.f,0.f), f1 = f0;
            if (r < N){
                const float* px = &x[(size_t)r*D + kc*32 + kb];
                f0 = *(const float4*)px;
                f1 = *(const float4*)(px + 4);
            }
            unsigned u0,u1,u2,u3;
            asm("v_cvt_pk_bf16_f32 %0, %1, %2" : "=v"(u0) : "v"(f0.x), "v"(f0.y));
            asm("v_cvt_pk_bf16_f32 %0, %1, %2" : "=v"(u1) : "v"(f0.z), "v"(f0.w));
            asm("v_cvt_pk_bf16_f32 %0, %1, %2" : "=v"(u2) : "v"(f1.x), "v"(f1.y));
            asm("v_cvt_pk_bf16_f32 %0, %1, %2" : "=v"(u3) : "v"(f1.z), "v"(f1.w));
            union { unsigned u[4]; short8 s; } uu = {{u0, u1, u2, u3}};
            a[kc] = uu.s;
        }
        const short8* __restrict__ wfr = (const short8*)wf;
        #pragma unroll
        for (int nt = 0; nt < 8; ++nt){
            f32x4 acc = {0.f, 0.f, 0.f, 0.f};
            #pragma unroll
            for (int kc = 0; kc < 4; ++kc)
                acc = __builtin_amdgcn_mfma_f32_16x16x32_bf16(
                          wfr[(nt*4 + kc)*64 + l], a[kc], acc, 0, 0, 0);
            int pk = __builtin_amdgcn_cvt_pk_fp8_f32(acc[0], acc[1], 0, false);
            pk     = __builtin_amdgcn_cvt_pk_fp8_f32(acc[2], acc[3], pk, true);
            if (r < N) xw8[(size_t)r*32 + nt*4 + (l >> 4)] = (unsigned)pk;
        }
    } else {
        int e = (b - nGemm)*256 + tid;
        if (e < E) atomicAdd(&deg[edst[e]], 1);
    }
}

// ---- exclusive scan of deg (1024/block) via wave shfl-scan ----
__global__ void k_scanA(const int* __restrict__ deg, int* __restrict__ offs,
                        int* __restrict__ bsum, int N){
    __shared__ int wsums[16];
    __shared__ int gtot;
    int tid = threadIdx.x, lane = tid & 63, wid = tid >> 6;
    int g = blockIdx.x*1024 + tid;
    int val = (g < N) ? deg[g] : 0;
    int inc = val;
    #pragma unroll
    for (int off=1; off<64; off<<=1){
        int t = __shfl_up(inc, off);
        if (lane >= off) inc += t;
    }
    if (lane == 63) wsums[wid] = inc;
    __syncthreads();
    if (wid == 0 && lane < 16){
        int t = wsums[lane];
        int i2 = t;
        #pragma unroll
        for (int off=1; off<16; off<<=1){
            int u = __shfl_up(i2, off);
            if (lane >= off) i2 += u;
        }
        wsums[lane] = i2 - t;           // exclusive
        if (lane == 15) gtot = i2;
    }
    __syncthreads();
    if (g < N) offs[g] = wsums[wid] + inc - val;
    if (tid == 0) bsum[blockIdx.x] = gtot;
}

// ---- finalize: cross-block prefix (nb<=64), offs, cursor, norm, ep ----
__global__ void k_scanC(int* __restrict__ offs, const int* __restrict__ bsum,
                        int* __restrict__ cursor, const int* __restrict__ deg,
                        float* __restrict__ norm, int2* __restrict__ ep,
                        const int* __restrict__ perm, int N){
    __shared__ int sbase;
    int tid = threadIdx.x;
    if (tid < 64){
        int val = (tid < (int)blockIdx.x) ? bsum[tid] : 0;
        for (int off=32; off>0; off>>=1) val += __shfl_down(val, off);
        if (tid == 0) sbase = val;
    }
    __syncthreads();
    int g = blockIdx.x*1024 + tid;
    if (g < N){
        int o = offs[g] + sbase;
        offs[g] = o;
        cursor[g] = o;
        float nm = rsqrtf(fmaxf((float)deg[g], 1.f));
        norm[g] = nm;
        ep[g] = make_int2(perm[g], __float_as_int(nm));
    }
}

// ---- fill CSR with full edge payload: epe[p] = {s | perm[s]<<16, norm[s]} ----
__global__ void k_fill(const int* __restrict__ src, const int* __restrict__ dst,
                       int* __restrict__ cursor, const int2* __restrict__ ep,
                       int2* __restrict__ epe, int E){
    int e = blockIdx.x*blockDim.x + threadIdx.x;
    if (e < E){
        int s  = src[e];
        int dd = dst[e];
        int p  = atomicAdd(&cursor[dd], 1);
        int2 eo = ep[s];
        epe[p] = make_int2(s | (eo.x << 16), eo.y);
    }
}

#define FMA8(u, nk) { \
    f32x2 f01 = __builtin_amdgcn_cvt_pk_f32_fp8((int)(u), false); \
    f32x2 f23 = __builtin_amdgcn_cvt_pk_f32_fp8((int)(u), true);  \
    ac.x = fmaf(f01.x, (nk), ac.x); ac.y = fmaf(f01.y, (nk), ac.y); \
    ac.z = fmaf(f23.x, (nk), ac.z); ac.w = fmaf(f23.y, (nk), ac.w); }

// ---- fused layer-1 agg (clean lanes 0-31, corrupt lanes 32-63) + relu + dot(v) ----
// prefetch is now ONE coalesced 8B load; zero random reads before row gathers
__global__ void __launch_bounds__(256) k_agg(const unsigned* __restrict__ xw8,
                     const int2* __restrict__ epe, const int* __restrict__ offs,
                     const int* __restrict__ deg, const float* __restrict__ norm,
                     const float* __restrict__ b1,
                     const float* __restrict__ v, float2* __restrict__ t2, int N){
    int w = threadIdx.x >> 6;
    int lane = threadIdx.x & 63;
    int i = blockIdx.x*4 + w;
    if (i >= N) return;
    int half = lane >> 5;
    int sh = half << 4;                               // 0 or 16
    int c = lane & 31;                                // uint column (4 dims)
    const unsigned* __restrict__ xr = xw8;            // row stride 32 uints (128B)
    float4 ac = make_float4(0.f,0.f,0.f,0.f);
    int start = offs[i], cnt = deg[i];

    for (int base = 0; base < cnt; base += 64){
        int m = min(cnt - base, 64);
        int ssp = 0; float ns = 0.f;
        if (lane < m){
            int2 t = epe[start + base + lane];
            ssp = t.x;
            ns = __int_as_float(t.y);
        }
        int k = 0;
        for (; k + 4 <= m; k += 4){
            int p0=__shfl(ssp,k  ); float n0=__shfl(ns,k  );
            int p1=__shfl(ssp,k+1); float n1=__shfl(ns,k+1);
            int p2=__shfl(ssp,k+2); float n2=__shfl(ns,k+2);
            int p3=__shfl(ssp,k+3); float n3=__shfl(ns,k+3);
            unsigned r0 = ((unsigned)p0 >> sh) & 0xffffu;
            unsigned r1 = ((unsigned)p1 >> sh) & 0xffffu;
            unsigned r2 = ((unsigned)p2 >> sh) & 0xffffu;
            unsigned r3 = ((unsigned)p3 >> sh) & 0xffffu;
            unsigned d0 = xr[(size_t)r0*32 + c];
            unsigned d1 = xr[(size_t)r1*32 + c];
            unsigned d2 = xr[(size_t)r2*32 + c];
            unsigned d3 = xr[(size_t)r3*32 + c];
            FMA8(d0, n0); FMA8(d1, n1); FMA8(d2, n2); FMA8(d3, n3);
        }
        for (; k < m; ++k){
            int pk_=__shfl(ssp,k); float nk=__shfl(ns,k);
            unsigned r = ((unsigned)pk_ >> sh) & 0xffffu;
            unsigned dv = xr[(size_t)r*32 + c];
            FMA8(dv, nk);
        }
    }
    float ni = norm[i];
    float4 bb = ((const float4*)b1)[c];
    float4 vv = ((const float4*)v)[c];
    float p = fmaxf(fmaf(ac.x, ni, bb.x), 0.f)*vv.x
            + fmaxf(fmaf(ac.y, ni, bb.y), 0.f)*vv.y
            + fmaxf(fmaf(ac.z, ni, bb.z), 0.f)*vv.z
            + fmaxf(fmaf(ac.w, ni, bb.w), 0.f)*vv.w;
    for (int off=16; off>0; off>>=1) p += __shfl_xor(p, off);
    float pd = __shfl(p, 32);
    if (lane == 0) t2[i] = make_float2(ni*p, ni*pd);
}

// ---- layer-2 scalar gather + loss + final (last-block) ----
__global__ void k_loss(const float2* __restrict__ t2, const int2* __restrict__ epe,
                       const int* __restrict__ offs, const int* __restrict__ deg,
                       const float* __restrict__ norm, const float* __restrict__ cconst,
                       float* __restrict__ acc, unsigned* __restrict__ done,
                       float* __restrict__ out, int N, int nblocks){
    int i = blockIdx.x*blockDim.x + threadIdx.x;
    float li = 0.f;
    if (i < N){
        int start = offs[i], cnt = deg[i];
        float sc = 0.f, sd = 0.f;
        for (int k=0;k<cnt;k++){
            int s = epe[start+k].x & 0xffff;
            float2 t = t2[s];
            sc += t.x; sd += t.y;
        }
        float ni = norm[i], C = cconst[0];
        li = softplusf(-fmaf(ni, sc, C)) + softplusf(fmaf(ni, sd, C));
    }
    for (int off=32; off>0; off>>=1) li += __shfl_down(li, off);
    __shared__ float wsum[4];
    int lane = threadIdx.x & 63, wid = threadIdx.x >> 6;
    if (lane == 0) wsum[wid] = li;
    __syncthreads();
    if (threadIdx.x == 0){
        float s = wsum[0] + wsum[1] + wsum[2] + wsum[3];
        atomicAdd(acc, s);
        __threadfence();
        unsigned t = atomicAdd(done, 1u);
        if (t == (unsigned)(nblocks - 1)){
            float tot = atomicAdd(acc, 0.0f);
            out[0] = tot / (float)(2*N);
        }
    }
}

extern "C" void kernel_launch(void* const* d_in, const int* in_sizes, int n_in,
                              void* d_out, int out_size, void* d_ws, size_t ws_size,
                              hipStream_t stream){
    const float* x    = (const float*)d_in[0];
    const float* W1   = (const float*)d_in[1];
    const float* b1   = (const float*)d_in[2];
    const float* W2   = (const float*)d_in[3];
    const float* b2   = (const float*)d_in[4];
    const float* Wp   = (const float*)d_in[5];
    const float* bp   = (const float*)d_in[6];
    const int*   esrc = (const int*)d_in[7];
    const int*   edst = (const int*)d_in[8];
    const int*   perm = (const int*)d_in[9];
    const int N = in_sizes[0] / D;
    const int E = in_sizes[7];

    char* ws = (char*)d_ws;
    size_t off = 0;
    auto alloc = [&](size_t bytes)->void*{
        void* p = ws + off;
        off += (bytes + 255) & ~(size_t)255;
        return p;
    };
    unsigned* xw8 = (unsigned*)alloc((size_t)N*32*sizeof(unsigned));   // fp8 rows, 128B
    unsigned short* wf = (unsigned short*)alloc((size_t)D*D*sizeof(unsigned short)); // W1 frags
    // deg and acc adjacent -> single memset clears both
    size_t degBytes = ((size_t)N*sizeof(int) + 255) & ~(size_t)255;
    int*   deg    = (int*)  alloc((size_t)N*sizeof(int));
    float* acc    = (float*)alloc(256);
    unsigned* done = (unsigned*)(acc + 1);
    float* norm   = (float*)alloc((size_t)N*sizeof(float));
    int*   offs   = (int*)  alloc((size_t)N*sizeof(int));
    int*   cursor = (int*)  alloc((size_t)N*sizeof(int));
    int2*  ep     = (int2*) alloc((size_t)N*sizeof(int2));
    int2*  epe    = (int2*) alloc((size_t)E*sizeof(int2));
    float2* t2    = (float2*)alloc((size_t)N*sizeof(float2));
    int*   bsum   = (int*)  alloc(4096);
    float* v      = (float*)alloc(D*sizeof(float));
    float* cconst = (float*)alloc(256);

    hipMemsetAsync(deg, 0, degBytes + 256, stream);

    int nGemm = (N + 63) / 64;
    int nDeg  = (E + 255) / 256;
    int nb    = (N + 1023) / 1024;
    int nLoss = (N + 255) / 256;

    k_prep  <<<9, 256, 0, stream>>>(W1, wf, W2, b2, Wp, bp, v, cconst);
    k_fused1<<<nGemm + nDeg, 256, 0, stream>>>(x, wf, xw8, N, edst, deg, E, nGemm);
    k_scanA <<<nb, 1024, 0, stream>>>(deg, offs, bsum, N);
    k_scanC <<<nb, 1024, 0, stream>>>(offs, bsum, cursor, deg, norm, ep, perm, N);
    k_fill  <<<(E+255)/256, 256, 0, stream>>>(esrc, edst, cursor, ep, epe, E);
    k_agg   <<<(N+3)/4, 256, 0, stream>>>(xw8, epe, offs, deg, norm, b1, v, t2, N);
    k_loss  <<<nLoss, 256, 0, stream>>>(t2, epe, offs, deg, norm, cconst, acc, done,
                                        (float*)d_out, N, nLoss);
}